// Round 6
// baseline (12402.926 us; speedup 1.0000x reference)
//
#include <hip/hip_runtime.h>

typedef unsigned short u16;
typedef unsigned int   u32;

typedef __attribute__((ext_vector_type(8)))  short bf16x8;
typedef __attribute__((ext_vector_type(4)))  float f32x4;
typedef __attribute__((ext_vector_type(16))) float f32x16;

#define B_  32
#define S_  1024
#define NH_ 512
#define G4_ 2048      // 4*NH
#define SC_NWG 32     // scan WGs (2 waves each = 64 wave-slots)
#define CAND   256    // election candidates (256 CUs, 1 WG/CU via LDS pad)

__device__ __forceinline__ float bf2f(u16 h) {
    return __uint_as_float(((u32)h) << 16);
}
__device__ __forceinline__ u16 f2bf(float f) {
    u32 u = __float_as_uint(f);
    return (u16)((u + 0x7fffu + ((u >> 16) & 1u)) >> 16);
}
__device__ __forceinline__ float fsig(float x) {
    return 1.0f / (1.0f + __expf(-x));
}
__device__ __forceinline__ float ftanh(float x) {
    return 1.0f - 2.0f / (__expf(2.0f * x) + 1.0f);
}

// ---------------- fp32 -> bf16 elementwise convert (vectorized x4) ----------
__global__ void cvt_bf16_kernel(const float* __restrict__ in, u16* __restrict__ out, int n4) {
    int i = blockIdx.x * blockDim.x + threadIdx.x;
    if (i >= n4) return;
    f32x4 v = ((const f32x4*)in)[i];
    unsigned long long pk =
        (unsigned long long)f2bf(v[0]) |
        ((unsigned long long)f2bf(v[1]) << 16) |
        ((unsigned long long)f2bf(v[2]) << 32) |
        ((unsigned long long)f2bf(v[3]) << 48);
    ((unsigned long long*)out)[i] = pk;
}

// ---------------- fp32 [R][C] -> bf16 [C][R] transpose-convert --------------
__global__ void transpose_cvt_kernel(const float* __restrict__ in, u16* __restrict__ out,
                                     int R, int C) {
    __shared__ float tile[32][33];
    int bx = blockIdx.x, by = blockIdx.y;
    int tx = threadIdx.x & 31, ty = threadIdx.x >> 5;
    #pragma unroll
    for (int i = 0; i < 4; i++) {
        int r = by * 32 + ty + i * 8;
        tile[ty + i * 8][tx] = in[(size_t)r * C + bx * 32 + tx];
    }
    __syncthreads();
    #pragma unroll
    for (int i = 0; i < 4; i++) {
        int c = bx * 32 + ty + i * 8;
        out[(size_t)c * R + by * 32 + tx] = f2bf(tile[tx][ty + i * 8]);
    }
}

// ---------------- generic bf16 MFMA GEMM: C = A @ BT^T + bias ---------------
// A [M][K] bf16 row-major, BT [N][K] bf16, bias [N] f32.
// out_mode: 0 -> f32 row-major; 1 -> bf16 in SCAN ORDER [t][wg64][lane][r]
__global__ __launch_bounds__(256) void gemm_bf16_kernel(
    const u16* __restrict__ A, const u16* __restrict__ BT,
    const float* __restrict__ bias, void* __restrict__ Cp,
    int M, int N, int K, int out_mode)
{
    __shared__ u16 Al[128][40];
    __shared__ u16 Bl[128][40];
    int nbm = M >> 7;
    int bm = blockIdx.x % nbm, bn = blockIdx.x / nbm;
    int tid = threadIdx.x, lane = tid & 63, wave = tid >> 6;
    int wr = wave >> 1, wc = wave & 1;
    f32x4 acc[4][4];
    #pragma unroll
    for (int i = 0; i < 4; i++)
        #pragma unroll
        for (int j = 0; j < 4; j++)
            acc[i][j] = (f32x4){0.f, 0.f, 0.f, 0.f};
    int fr  = lane & 15;
    int kof = (lane >> 4) << 3;

    for (int k0 = 0; k0 < K; k0 += 32) {
        __syncthreads();
        #pragma unroll
        for (int i = 0; i < 2; i++) {
            int chunk = i * 256 + tid;
            int r = chunk >> 2, c = (chunk & 3) << 3;
            *(bf16x8*)&Al[r][c] = *(const bf16x8*)&A[(size_t)(bm * 128 + r) * K + k0 + c];
            *(bf16x8*)&Bl[r][c] = *(const bf16x8*)&BT[(size_t)(bn * 128 + r) * K + k0 + c];
        }
        __syncthreads();
        bf16x8 af[4], bfr[4];
        #pragma unroll
        for (int mi = 0; mi < 4; mi++)
            af[mi] = *(const bf16x8*)&Al[wr * 64 + mi * 16 + fr][kof];
        #pragma unroll
        for (int ni = 0; ni < 4; ni++)
            bfr[ni] = *(const bf16x8*)&Bl[wc * 64 + ni * 16 + fr][kof];
        #pragma unroll
        for (int mi = 0; mi < 4; mi++)
            #pragma unroll
            for (int ni = 0; ni < 4; ni++)
                acc[mi][ni] = __builtin_amdgcn_mfma_f32_16x16x32_bf16(af[mi], bfr[ni], acc[mi][ni], 0, 0, 0);
    }
    int rq = lane >> 4;
    #pragma unroll
    for (int mi = 0; mi < 4; mi++) {
        #pragma unroll
        for (int ni = 0; ni < 4; ni++) {
            int n = bn * 128 + wc * 64 + ni * 16 + fr;
            float bv = bias ? bias[n] : 0.f;
            #pragma unroll
            for (int r = 0; r < 4; r++) {
                int m = bm * 128 + wr * 64 + mi * 16 + rq * 4 + r;
                float v = acc[mi][ni][r] + bv;
                if (out_mode == 1) {
                    // scan-order store: [t][wg64][lane2][r2]  (validated round 4)
                    int t = m & 1023, b = m >> 10;
                    int g_loc = n >> 9, wg64i = (n >> 3) & 63, u_loc = n & 7;
                    int lane2 = (((b >> 2) & 1) << 5) | (u_loc << 2) | g_loc;
                    int r2 = (b & 3) | ((b >> 3) << 2);
                    ((u16*)Cp)[(((size_t)t * 64 + wg64i) * 64 + lane2) * 16 + r2] = f2bf(v);
                } else {
                    ((float*)Cp)[(size_t)m * N + n] = v;
                }
            }
        }
    }
}

// ---------------- LSTM scan: 32 same-XCD WGs x 2 waves ----------------------
// Election: 256 candidates (1/CU via LDS pad) read HW_REG_XCC_ID; first XCD
// to register 32 WGs wins (agent-scope atomics, bounded waits). Winners get
// roles 0..31; rest exit.
// Per-step messaging is entirely intra-XCD-L2:
//   producer wave: plain h stores -> s_waitcnt vmcnt(0) (h committed to the
//   shared L2) -> plain sentinel store sent[wg64]=t+1.
//   consumer: poll = buffer_inv (invalidate own L1) + plain 4B/lane load of
//   all 64 sentinels; after 64 failed rounds fall back to atomic-or-return
//   (executes at L2, L1-bypassing, guaranteed fresh); hard cap on rounds so
//   no configuration can hang. Sentinel >= t for all 64 slots implies h(t)
//   is in L2 AND every wave finished reading h(t-1) (publish comes after its
//   reads), so the 2-deep hbuf ping-pong is overwrite-safe.
__global__ __launch_bounds__(128, 1) void lstm_scan_kernel(
    const u16* __restrict__ xw,    // [S][64][64][16] bf16 scan-order
    const u16* __restrict__ UT,    // [4H][NH] bf16
    u16* __restrict__ hseq,        // [B][S][NH] bf16
    u16* __restrict__ hbuf,        // [2][32][512] bf16
    u32* __restrict__ sent,        // [64] per-wave-slot sentinels
    u32* __restrict__ elect,       // [8] per-XCD registration counters
    int* __restrict__ winner)      // winning XCD id, init -1
{
    __shared__ int s_role;
    __shared__ u16 h_lds[32][520];      // [batch][k], +8 u16 pad (0-conflict, r2)
    __shared__ float gl[2][32][32];     // per-wave gate exchange
    __shared__ u16 lds_pad[25088];      // 50KB: force 1 WG/CU (92KB total LDS)

    const int tid = threadIdx.x;
    lds_pad[tid] = (u16)tid;            // keep the pad alive

    if (tid == 0) {
        u32 xcc;
        asm volatile("s_getreg_b32 %0, hwreg(HW_REG_XCC_ID)" : "=s"(xcc));
        xcc &= 7u;
        u32 r = __hip_atomic_fetch_add(&elect[xcc], 1u,
                    __ATOMIC_ACQ_REL, __HIP_MEMORY_SCOPE_AGENT);
        int role = -1;
        if (r < (u32)SC_NWG) {
            if (r == (u32)SC_NWG - 1) {  // our XCD just reached 32: try claim
                int expv = -1;
                __hip_atomic_compare_exchange_strong(winner, &expv, (int)xcc,
                    __ATOMIC_ACQ_REL, __ATOMIC_ACQUIRE, __HIP_MEMORY_SCOPE_AGENT);
            }
            int w = -1;
            for (long spins = 0; spins < 20000000L; spins++) {   // bounded
                w = __hip_atomic_load(winner, __ATOMIC_ACQUIRE,
                                      __HIP_MEMORY_SCOPE_AGENT);
                if (w >= 0) break;
                __builtin_amdgcn_s_sleep(8);
            }
            role = (w == (int)xcc) ? (int)r : -1;
        }
        s_role = role;
    }
    __syncthreads();
    const int role = s_role;
    if (role < 0) return;

    const int wave = tid >> 6, lane = tid & 63;
    const int wg64 = role * 2 + wave;
    const int col  = lane & 31, half = lane >> 5;
    const int u_loc = col >> 2, g_loc = col & 3;
    const int ucol  = g_loc * 512 + wg64 * 8 + u_loc;

    // persistent U B-fragments: zero weight traffic in the loop
    bf16x8 ufrag[32];
    #pragma unroll
    for (int kk = 0; kk < 32; kk++)
        ufrag[kk] = *(const bf16x8*)&UT[(size_t)ucol * 512 + kk * 16 + half * 8];

    float cst[4] = {0.f, 0.f, 0.f, 0.f};

    // h(0) = 0 in LDS (t=0 skips the poll)
    {
        bf16x8 z = (bf16x8){0, 0, 0, 0, 0, 0, 0, 0};
        bf16x8* hf = (bf16x8*)&h_lds[0][0];
        for (int i = tid; i < 2080; i += 128) hf[i] = z;
    }

    const int sb_b  = tid >> 4;   // base row 0..7 (rows sb_b + 8k, k=0..3)
    const int sb_ic = tid & 15;   // 16B chunk, 256B-strided (0-conflict, r2)
    const u32* sp = sent + lane;  // each lane polls one wave-slot

    for (int t = 0; t < 1024; t++) {
        // xw for this step: 32B contiguous per lane, issued early
        const u16* xp = xw + ((size_t)((size_t)t * 64 + wg64) * 64 + lane) * 16;
        bf16x8 xv0 = *(const bf16x8*)xp;
        bf16x8 xv1 = *(const bf16x8*)(xp + 8);

        if (t > 0) {
            int rounds = 0;
            while (1) {
                u32 sv;
                if (rounds < 64) {
                    // primary: invalidate own L1, fresh read from shared L2
                    asm volatile("buffer_inv\n\t"
                                 "s_waitcnt vmcnt(0)\n\t"
                                 "global_load_dword %0, %1, off\n\t"
                                 "s_waitcnt vmcnt(0)"
                                 : "=v"(sv) : "v"(sp) : "memory");
                } else {
                    // fallback: atomic-or 0 returns old, executes at L2
                    asm volatile("global_atomic_or %0, %1, %2, off sc0\n\t"
                                 "s_waitcnt vmcnt(0)"
                                 : "=v"(sv) : "v"(sp), "v"(0u) : "memory");
                    __builtin_amdgcn_s_sleep(2);
                }
                if (__all((int)(sv >= (u32)t))) break;
                if (++rounds > 16384) break;   // hard cap: never hang
            }
            // one more L1 invalidate so bulk h loads refill from L2
            asm volatile("buffer_inv\n\ts_waitcnt vmcnt(0)" ::: "memory");

            const char* sb0 = (const char*)(hbuf + ((size_t)(t & 1) << 14))
                              + sb_b * 1024 + sb_ic * 16;
            f32x4 r0, r1, r2, r3, r4, r5, r6, r7;
            // rows sb_b, sb_b+8 (k=0,1)
            asm volatile(
                "global_load_dwordx4 %0, %8, off\n\t"
                "global_load_dwordx4 %1, %8, off offset:256\n\t"
                "global_load_dwordx4 %2, %8, off offset:512\n\t"
                "global_load_dwordx4 %3, %8, off offset:768\n\t"
                "global_load_dwordx4 %4, %9, off\n\t"
                "global_load_dwordx4 %5, %9, off offset:256\n\t"
                "global_load_dwordx4 %6, %9, off offset:512\n\t"
                "global_load_dwordx4 %7, %9, off offset:768\n\t"
                "s_waitcnt vmcnt(0)"
                : "=&v"(r0), "=&v"(r1), "=&v"(r2), "=&v"(r3),
                  "=&v"(r4), "=&v"(r5), "=&v"(r6), "=&v"(r7)
                : "v"(sb0), "v"(sb0 + 8192) : "memory");
            {
                u16* d0 = &h_lds[sb_b][sb_ic * 8];
                u16* d1 = &h_lds[sb_b + 8][sb_ic * 8];
                *(f32x4*)(d0) = r0; *(f32x4*)(d0 + 128) = r1;
                *(f32x4*)(d0 + 256) = r2; *(f32x4*)(d0 + 384) = r3;
                *(f32x4*)(d1) = r4; *(f32x4*)(d1 + 128) = r5;
                *(f32x4*)(d1 + 256) = r6; *(f32x4*)(d1 + 384) = r7;
            }
            // rows sb_b+16, sb_b+24 (k=2,3)
            asm volatile(
                "global_load_dwordx4 %0, %8, off\n\t"
                "global_load_dwordx4 %1, %8, off offset:256\n\t"
                "global_load_dwordx4 %2, %8, off offset:512\n\t"
                "global_load_dwordx4 %3, %8, off offset:768\n\t"
                "global_load_dwordx4 %4, %9, off\n\t"
                "global_load_dwordx4 %5, %9, off offset:256\n\t"
                "global_load_dwordx4 %6, %9, off offset:512\n\t"
                "global_load_dwordx4 %7, %9, off offset:768\n\t"
                "s_waitcnt vmcnt(0)"
                : "=&v"(r0), "=&v"(r1), "=&v"(r2), "=&v"(r3),
                  "=&v"(r4), "=&v"(r5), "=&v"(r6), "=&v"(r7)
                : "v"(sb0 + 16384), "v"(sb0 + 24576) : "memory");
            {
                u16* d2 = &h_lds[sb_b + 16][sb_ic * 8];
                u16* d3 = &h_lds[sb_b + 24][sb_ic * 8];
                *(f32x4*)(d2) = r0; *(f32x4*)(d2 + 128) = r1;
                *(f32x4*)(d2 + 256) = r2; *(f32x4*)(d2 + 384) = r3;
                *(f32x4*)(d3) = r4; *(f32x4*)(d3 + 128) = r5;
                *(f32x4*)(d3 + 256) = r6; *(f32x4*)(d3 + 384) = r7;
            }
        }
        __syncthreads();   // h_lds fully staged by both waves

        // gates = h @ Uslice: 2 accumulators halve the dependent-MFMA chain
        f32x16 a0 = {0,0,0,0, 0,0,0,0, 0,0,0,0, 0,0,0,0};
        f32x16 a1 = {0,0,0,0, 0,0,0,0, 0,0,0,0, 0,0,0,0};
        #pragma unroll
        for (int kk = 0; kk < 16; kk++) {
            bf16x8 af0 = *(const bf16x8*)&h_lds[col][kk * 16 + half * 8];
            a0 = __builtin_amdgcn_mfma_f32_32x32x16_bf16(af0, ufrag[kk], a0, 0, 0, 0);
            bf16x8 af1 = *(const bf16x8*)&h_lds[col][(kk + 16) * 16 + half * 8];
            a1 = __builtin_amdgcn_mfma_f32_32x32x16_bf16(af1, ufrag[kk + 16], a1, 0, 0, 0);
        }

        // gate exchange (wave-local LDS; compiler orders via lgkmcnt)
        #pragma unroll
        for (int r = 0; r < 16; r++) {
            int b = (r & 3) + ((r >> 2) << 3) + (half << 2);
            float xwv = bf2f(r < 8 ? (u16)xv0[r] : (u16)xv1[r - 8]);
            gl[wave][b][col] = a0[r] + a1[r] + xwv;
        }

        // cell update: each lane owns 4 (batch,unit) pairs of this wave-slot
        u16* hb_out = hbuf + ((size_t)(((size_t)t + 1) & 1) << 14);
        #pragma unroll
        for (int i = 0; i < 4; i++) {
            int p = (i << 6) + lane, b = p >> 3, u = p & 7;
            f32x4 g4 = *(const f32x4*)&gl[wave][b][u << 2];   // i,f,g,o
            float si = fsig(g4[0]), sf = fsig(g4[1]);
            float sg = ftanh(g4[2]), so = fsig(g4[3]);
            float c = sf * cst[i] + si * sg;
            cst[i] = c;
            float h = so * ftanh(c);
            u16 hv = f2bf(h);
            int j = (wg64 << 3) + u;
            hseq[((size_t)b * S_ + t) * NH_ + j] = hv;   // plain, read post-kernel
            hb_out[b * NH_ + j] = hv;                    // plain -> shared L2
        }
        // drain this wave's stores to L2, then publish this wave's sentinel
        asm volatile("s_waitcnt vmcnt(0)" ::: "memory");
        if (lane == 0) {
            u32 fv = (u32)(t + 1);
            u32* fq = sent + wg64;
            asm volatile("global_store_dword %0, %1, off"
                         :: "v"(fq), "v"(fv) : "memory");
        }
    }
}

extern "C" void kernel_launch(void* const* d_in, const int* in_sizes, int n_in,
                              void* d_out, int out_size, void* d_ws, size_t ws_size,
                              hipStream_t stream) {
    const float* x        = (const float*)d_in[0];
    const float* W        = (const float*)d_in[1];
    const float* U        = (const float*)d_in[2];
    const float* hid_bias = (const float*)d_in[3];
    const float* V        = (const float*)d_in[4];
    const float* out_bias = (const float*)d_in[5];

    char* ws = (char*)d_ws;
    size_t off = 0;
    auto carve = [&](size_t bytes) -> void* {
        void* p = ws + off;
        off += (bytes + 255) & ~(size_t)255;
        return p;
    };
    u16* xw     = (u16*)carve((size_t)B_ * S_ * G4_ * 2);   // 128 MB, scan-order
    u16* xbf    = (u16*)carve((size_t)B_ * S_ * NH_ * 2);   //  32 MB
    u16* hseq   = (u16*)carve((size_t)B_ * S_ * NH_ * 2);   //  32 MB
    u16* WT     = (u16*)carve((size_t)G4_ * NH_ * 2);       //   2 MB
    u16* UT     = (u16*)carve((size_t)G4_ * NH_ * 2);       //   2 MB
    u16* VT     = (u16*)carve((size_t)NH_ * NH_ * 2);       // 512 KB
    u16* hbuf   = (u16*)carve((size_t)2 * B_ * NH_ * 2);    //  64 KB
    u32* sentn  = (u32*)carve(256);
    u32* elect  = (u32*)carve(256);
    int* winner = (int*)carve(256);

    hipMemsetAsync(sentn, 0, 256, stream);
    hipMemsetAsync(elect, 0, 256, stream);
    hipMemsetAsync(winner, 0xFF, 256, stream);   // winner = -1

    int n4 = B_ * S_ * NH_ / 4;
    cvt_bf16_kernel<<<(n4 + 255) / 256, 256, 0, stream>>>(x, xbf, n4);
    transpose_cvt_kernel<<<dim3(G4_ / 32, NH_ / 32), 256, 0, stream>>>(W, WT, NH_, G4_);
    transpose_cvt_kernel<<<dim3(G4_ / 32, NH_ / 32), 256, 0, stream>>>(U, UT, NH_, G4_);
    transpose_cvt_kernel<<<dim3(NH_ / 32, NH_ / 32), 256, 0, stream>>>(V, VT, NH_, NH_);

    // xW + hid_bias -> bf16, stored in scan order
    gemm_bf16_kernel<<<4096, 256, 0, stream>>>(xbf, WT, hid_bias, xw,
                                               B_ * S_, G4_, NH_, 1);
    // sequential LSTM scan (same-XCD election inside)
    lstm_scan_kernel<<<CAND, 128, 0, stream>>>(xw, UT, hseq, hbuf,
                                               sentn, elect, winner);
    // out = hseq @ V + out_bias -> f32
    gemm_bf16_kernel<<<1024, 256, 0, stream>>>(hseq, VT, out_bias, d_out,
                                               B_ * S_, NH_, NH_, 0);
}

// Round 7
// 6424.635 us; speedup vs baseline: 1.9305x; 1.9305x over previous
//
#include <hip/hip_runtime.h>

typedef unsigned short u16;
typedef unsigned int   u32;

typedef __attribute__((ext_vector_type(8)))  short bf16x8;
typedef __attribute__((ext_vector_type(4)))  float f32x4;
typedef __attribute__((ext_vector_type(4)))  u32   u32x4;
typedef __attribute__((ext_vector_type(16))) float f32x16;

#define B_  32
#define S_  1024
#define NH_ 512
#define G4_ 2048   // 4*NH
#define SC_NWG 8   // scan workgroups (8 waves each = 64 wave-slots)

__device__ __forceinline__ float bf2f(u16 h) {
    return __uint_as_float(((u32)h) << 16);
}
__device__ __forceinline__ u16 f2bf(float f) {
    u32 u = __float_as_uint(f);
    return (u16)((u + 0x7fffu + ((u >> 16) & 1u)) >> 16);
}
__device__ __forceinline__ float fsig(float x) {
    return 1.0f / (1.0f + __expf(-x));
}
__device__ __forceinline__ float ftanh(float x) {
    return 1.0f - 2.0f / (__expf(2.0f * x) + 1.0f);
}

// ---------------- fp32 -> bf16 elementwise convert (vectorized x4) ----------
__global__ void cvt_bf16_kernel(const float* __restrict__ in, u16* __restrict__ out, int n4) {
    int i = blockIdx.x * blockDim.x + threadIdx.x;
    if (i >= n4) return;
    f32x4 v = ((const f32x4*)in)[i];
    unsigned long long pk =
        (unsigned long long)f2bf(v[0]) |
        ((unsigned long long)f2bf(v[1]) << 16) |
        ((unsigned long long)f2bf(v[2]) << 32) |
        ((unsigned long long)f2bf(v[3]) << 48);
    ((unsigned long long*)out)[i] = pk;
}

// ---------------- fp32 [R][C] -> bf16 [C][R] transpose-convert --------------
__global__ void transpose_cvt_kernel(const float* __restrict__ in, u16* __restrict__ out,
                                     int R, int C) {
    __shared__ float tile[32][33];
    int bx = blockIdx.x, by = blockIdx.y;
    int tx = threadIdx.x & 31, ty = threadIdx.x >> 5;
    #pragma unroll
    for (int i = 0; i < 4; i++) {
        int r = by * 32 + ty + i * 8;
        tile[ty + i * 8][tx] = in[(size_t)r * C + bx * 32 + tx];
    }
    __syncthreads();
    #pragma unroll
    for (int i = 0; i < 4; i++) {
        int c = bx * 32 + ty + i * 8;
        out[(size_t)c * R + by * 32 + tx] = f2bf(tile[tx][ty + i * 8]);
    }
}

// ---------------- generic bf16 MFMA GEMM: C = A @ BT^T + bias ---------------
// A [M][K] bf16 row-major, BT [N][K] bf16, bias [N] f32.
// out_mode: 0 -> f32 row-major; 1 -> bf16 in SCAN ORDER [t][wg64][lane][r]
__global__ __launch_bounds__(256) void gemm_bf16_kernel(
    const u16* __restrict__ A, const u16* __restrict__ BT,
    const float* __restrict__ bias, void* __restrict__ Cp,
    int M, int N, int K, int out_mode)
{
    __shared__ u16 Al[128][40];
    __shared__ u16 Bl[128][40];
    int nbm = M >> 7;
    int bm = blockIdx.x % nbm, bn = blockIdx.x / nbm;
    int tid = threadIdx.x, lane = tid & 63, wave = tid >> 6;
    int wr = wave >> 1, wc = wave & 1;
    f32x4 acc[4][4];
    #pragma unroll
    for (int i = 0; i < 4; i++)
        #pragma unroll
        for (int j = 0; j < 4; j++)
            acc[i][j] = (f32x4){0.f, 0.f, 0.f, 0.f};
    int fr  = lane & 15;
    int kof = (lane >> 4) << 3;

    for (int k0 = 0; k0 < K; k0 += 32) {
        __syncthreads();
        #pragma unroll
        for (int i = 0; i < 2; i++) {
            int chunk = i * 256 + tid;
            int r = chunk >> 2, c = (chunk & 3) << 3;
            *(bf16x8*)&Al[r][c] = *(const bf16x8*)&A[(size_t)(bm * 128 + r) * K + k0 + c];
            *(bf16x8*)&Bl[r][c] = *(const bf16x8*)&BT[(size_t)(bn * 128 + r) * K + k0 + c];
        }
        __syncthreads();
        bf16x8 af[4], bfr[4];
        #pragma unroll
        for (int mi = 0; mi < 4; mi++)
            af[mi] = *(const bf16x8*)&Al[wr * 64 + mi * 16 + fr][kof];
        #pragma unroll
        for (int ni = 0; ni < 4; ni++)
            bfr[ni] = *(const bf16x8*)&Bl[wc * 64 + ni * 16 + fr][kof];
        #pragma unroll
        for (int mi = 0; mi < 4; mi++)
            #pragma unroll
            for (int ni = 0; ni < 4; ni++)
                acc[mi][ni] = __builtin_amdgcn_mfma_f32_16x16x32_bf16(af[mi], bfr[ni], acc[mi][ni], 0, 0, 0);
    }
    int rq = lane >> 4;
    #pragma unroll
    for (int mi = 0; mi < 4; mi++) {
        #pragma unroll
        for (int ni = 0; ni < 4; ni++) {
            int n = bn * 128 + wc * 64 + ni * 16 + fr;
            float bv = bias ? bias[n] : 0.f;
            #pragma unroll
            for (int r = 0; r < 4; r++) {
                int m = bm * 128 + wr * 64 + mi * 16 + rq * 4 + r;
                float v = acc[mi][ni][r] + bv;
                if (out_mode == 1) {
                    // scan-order store: [t][wg64][lane2][r2]  (validated round 4)
                    int t = m & 1023, b = m >> 10;
                    int g_loc = n >> 9, wg64i = (n >> 3) & 63, u_loc = n & 7;
                    int lane2 = (((b >> 2) & 1) << 5) | (u_loc << 2) | g_loc;
                    int r2 = (b & 3) | ((b >> 3) << 2);
                    ((u16*)Cp)[(((size_t)t * 64 + wg64i) * 64 + lane2) * 16 + r2] = f2bf(v);
                } else {
                    ((float*)Cp)[(size_t)m * N + n] = v;
                }
            }
        }
    }
}

// ---------------- LSTM scan: 8 persistent WGs x 8 waves ---------------------
// Fire-and-forget tagged exchange, system scope (sc0 sc1 -- verified r2/r4):
// h words are u32 (tag<<16 | bf16), tag = t+1, in hbuf[2][32][512].
// Consumer thread: (1) spin on ONE 4B word of its 128B slice (cheap rounds),
// (2) bulk-read the slice once, validate all 32 tags, retry only on miss.
// No producer drain, no flags, one __syncthreads per step.
// Overwrite safety: a wave publishes tag t+1 only AFTER its WG's staging
// threads finished reading buf[(t)&1] (publish is after the staging barrier
// + MFMA), and a producer can only rewrite a buffer parity after seeing ALL
// waves' tags for the intermediate step -- induction gives 2-deep safety.
// Replay safety: stale tags from a previous graph replay are killed by this
// replay's earlier same-parity writes before any poll can match them.
__global__ __launch_bounds__(512, 2) void lstm_scan_kernel(
    const u16* __restrict__ xw,    // [S][64][64][16] bf16 scan-order
    const u16* __restrict__ UT,    // [4H][NH] bf16
    u16* __restrict__ hseq,        // [B][S][NH] bf16
    u32* __restrict__ hbuf)        // [2][32][512] u32 tagged h
{
    __shared__ u16 h_lds[32][520];      // [batch][k], +8 u16 pad (0-conflict, r2)
    __shared__ float gl[8][32][32];     // per-wave gate exchange

    const int tid  = threadIdx.x;
    const int wave = tid >> 6, lane = tid & 63;
    const int wg64 = (int)blockIdx.x * 8 + wave;
    const int col  = lane & 31, half = lane >> 5;
    const int u_loc = col >> 2, g_loc = col & 3;
    const int ucol  = g_loc * 512 + wg64 * 8 + u_loc;

    // persistent U B-fragments (128 VGPRs/lane; launch_bounds(512,2) gives a
    // 256-reg budget so these stay resident instead of re-loading per step)
    bf16x8 ufrag[32];
    #pragma unroll
    for (int kk = 0; kk < 32; kk++)
        ufrag[kk] = *(const bf16x8*)&UT[(size_t)ucol * 512 + kk * 16 + half * 8];

    float cst[4] = {0.f, 0.f, 0.f, 0.f};

    // h(0) = 0 in LDS (t=0 skips the poll)
    {
        bf16x8 z = (bf16x8){0, 0, 0, 0, 0, 0, 0, 0};
        bf16x8* hf = (bf16x8*)&h_lds[0][0];
        for (int i = tid; i < 2080; i += 512) hf[i] = z;
    }

    const int sb_b = tid >> 4;          // batch row this thread stages
    const int sb_i = tid & 15;          // 8-u32 (32B) chunk id within the row

    for (int t = 0; t < 1024; t++) {
        // xw for this step: 32B contiguous per lane, issued early
        const u16* xp = xw + ((size_t)((size_t)t * 64 + wg64) * 64 + lane) * 16;
        bf16x8 xv0 = *(const bf16x8*)xp;
        bf16x8 xv1 = *(const bf16x8*)(xp + 8);

        if (t > 0) {
            const u32 tg = (u32)t;
            const u32* src = hbuf + (((size_t)t & 1) << 14) + sb_b * 512 + sb_i * 8;
            // phase 1: cheap 4B spin on the first word of our slice
            {
                u32 f;
                int rounds = 0;
                do {
                    asm volatile("global_load_dword %0, %1, off sc0 sc1\n\t"
                                 "s_waitcnt vmcnt(0)"
                                 : "=v"(f) : "v"(src) : "memory");
                } while ((f >> 16) != tg && ++rounds < (1 << 17));
            }
            // phase 2: bulk-read slice (4 chunks of 8 u32, 512B apart),
            // validate every tag; retry on miss (rare)
            u32x4 v0, v1, v2, v3, v4, v5, v6, v7;
            int retries = 0;
            while (1) {
                asm volatile(
                    "global_load_dwordx4 %0, %8, off sc0 sc1\n\t"
                    "global_load_dwordx4 %1, %8, off offset:16 sc0 sc1\n\t"
                    "global_load_dwordx4 %2, %8, off offset:512 sc0 sc1\n\t"
                    "global_load_dwordx4 %3, %8, off offset:528 sc0 sc1\n\t"
                    "global_load_dwordx4 %4, %8, off offset:1024 sc0 sc1\n\t"
                    "global_load_dwordx4 %5, %8, off offset:1040 sc0 sc1\n\t"
                    "global_load_dwordx4 %6, %8, off offset:1536 sc0 sc1\n\t"
                    "global_load_dwordx4 %7, %8, off offset:1552 sc0 sc1\n\t"
                    "s_waitcnt vmcnt(0)"
                    : "=&v"(v0), "=&v"(v1), "=&v"(v2), "=&v"(v3),
                      "=&v"(v4), "=&v"(v5), "=&v"(v6), "=&v"(v7)
                    : "v"(src) : "memory");
                u32 bad = 0;
                #pragma unroll
                for (int j = 0; j < 4; j++) {
                    bad |= (v0[j] >> 16) ^ tg; bad |= (v1[j] >> 16) ^ tg;
                    bad |= (v2[j] >> 16) ^ tg; bad |= (v3[j] >> 16) ^ tg;
                    bad |= (v4[j] >> 16) ^ tg; bad |= (v5[j] >> 16) ^ tg;
                    bad |= (v6[j] >> 16) ^ tg; bad |= (v7[j] >> 16) ^ tg;
                }
                if (!bad || ++retries > (1 << 14)) break;
            }
            __builtin_amdgcn_sched_barrier(0);
            // pack pairs -> bf16, write 4x16B at 256B stride (0-conflict, r2)
            u16* d = &h_lds[sb_b][sb_i * 8];
            u32x4 p;
            p[0] = (v0[0] & 0xffffu) | (v0[1] << 16);
            p[1] = (v0[2] & 0xffffu) | (v0[3] << 16);
            p[2] = (v1[0] & 0xffffu) | (v1[1] << 16);
            p[3] = (v1[2] & 0xffffu) | (v1[3] << 16);
            *(u32x4*)(d) = p;
            p[0] = (v2[0] & 0xffffu) | (v2[1] << 16);
            p[1] = (v2[2] & 0xffffu) | (v2[3] << 16);
            p[2] = (v3[0] & 0xffffu) | (v3[1] << 16);
            p[3] = (v3[2] & 0xffffu) | (v3[3] << 16);
            *(u32x4*)(d + 128) = p;
            p[0] = (v4[0] & 0xffffu) | (v4[1] << 16);
            p[1] = (v4[2] & 0xffffu) | (v4[3] << 16);
            p[2] = (v5[0] & 0xffffu) | (v5[1] << 16);
            p[3] = (v5[2] & 0xffffu) | (v5[3] << 16);
            *(u32x4*)(d + 256) = p;
            p[0] = (v6[0] & 0xffffu) | (v6[1] << 16);
            p[1] = (v6[2] & 0xffffu) | (v6[3] << 16);
            p[2] = (v7[0] & 0xffffu) | (v7[1] << 16);
            p[3] = (v7[2] & 0xffffu) | (v7[3] << 16);
            *(u32x4*)(d + 384) = p;
        }
        __syncthreads();

        // gates = h @ Uslice: 2 accumulators halve the dependent-MFMA chain
        f32x16 a0 = {0,0,0,0, 0,0,0,0, 0,0,0,0, 0,0,0,0};
        f32x16 a1 = {0,0,0,0, 0,0,0,0, 0,0,0,0, 0,0,0,0};
        #pragma unroll
        for (int kk = 0; kk < 16; kk++) {
            bf16x8 af0 = *(const bf16x8*)&h_lds[col][kk * 16 + half * 8];
            a0 = __builtin_amdgcn_mfma_f32_32x32x16_bf16(af0, ufrag[kk], a0, 0, 0, 0);
            bf16x8 af1 = *(const bf16x8*)&h_lds[col][(kk + 16) * 16 + half * 8];
            a1 = __builtin_amdgcn_mfma_f32_32x32x16_bf16(af1, ufrag[kk + 16], a1, 0, 0, 0);
        }

        // gate exchange (wave-local LDS; in-wave lgkmcnt ordering, no barrier)
        #pragma unroll
        for (int r = 0; r < 16; r++) {
            int b = (r & 3) + ((r >> 2) << 3) + (half << 2);
            float xwv = bf2f(r < 8 ? (u16)xv0[r] : (u16)xv1[r - 8]);
            gl[wave][b][col] = a0[r] + a1[r] + xwv;
        }

        // cell update: each lane owns 4 (batch,unit) pairs
        u32* hb_out = hbuf + ((size_t)(((size_t)t + 1) & 1) << 14);
        const u32 tg1 = ((u32)(t + 1)) << 16;
        #pragma unroll
        for (int i = 0; i < 4; i++) {
            int p = (i << 6) + lane, b = p >> 3, u = p & 7;
            f32x4 g4 = *(const f32x4*)&gl[wave][b][u << 2];   // i,f,g,o
            float si = fsig(g4[0]), sf = fsig(g4[1]);
            float sg = ftanh(g4[2]), so = fsig(g4[3]);
            float c = sf * cst[i] + si * sg;
            cst[i] = c;
            float h = so * ftanh(c);
            u16 hv = f2bf(h);
            int j = (wg64 << 3) + u;
            hseq[((size_t)b * S_ + t) * NH_ + j] = hv;        // cached; read later
            u32 pk = tg1 | (u32)hv;
            u32* hp = hb_out + b * 512 + j;
            asm volatile("global_store_dword %0, %1, off sc0 sc1"
                         :: "v"(hp), "v"(pk) : "memory");
        }
        // fire-and-forget: no drain, no flag, no second barrier
    }
}

extern "C" void kernel_launch(void* const* d_in, const int* in_sizes, int n_in,
                              void* d_out, int out_size, void* d_ws, size_t ws_size,
                              hipStream_t stream) {
    const float* x        = (const float*)d_in[0];
    const float* W        = (const float*)d_in[1];
    const float* U        = (const float*)d_in[2];
    const float* hid_bias = (const float*)d_in[3];
    const float* V        = (const float*)d_in[4];
    const float* out_bias = (const float*)d_in[5];

    char* ws = (char*)d_ws;
    size_t off = 0;
    auto carve = [&](size_t bytes) -> void* {
        void* p = ws + off;
        off += (bytes + 255) & ~(size_t)255;
        return p;
    };
    u16* xw    = (u16*)carve((size_t)B_ * S_ * G4_ * 2);   // 128 MB, scan-order
    u16* xbf   = (u16*)carve((size_t)B_ * S_ * NH_ * 2);   //  32 MB
    u16* hseq  = (u16*)carve((size_t)B_ * S_ * NH_ * 2);   //  32 MB
    u16* WT    = (u16*)carve((size_t)G4_ * NH_ * 2);       //   2 MB
    u16* UT    = (u16*)carve((size_t)G4_ * NH_ * 2);       //   2 MB
    u16* VT    = (u16*)carve((size_t)NH_ * NH_ * 2);       // 512 KB
    u32* hbuf  = (u32*)carve((size_t)2 * B_ * NH_ * 4);    // 128 KB tagged h

    int n4 = B_ * S_ * NH_ / 4;
    cvt_bf16_kernel<<<(n4 + 255) / 256, 256, 0, stream>>>(x, xbf, n4);
    transpose_cvt_kernel<<<dim3(G4_ / 32, NH_ / 32), 256, 0, stream>>>(W, WT, NH_, G4_);
    transpose_cvt_kernel<<<dim3(G4_ / 32, NH_ / 32), 256, 0, stream>>>(U, UT, NH_, G4_);
    transpose_cvt_kernel<<<dim3(NH_ / 32, NH_ / 32), 256, 0, stream>>>(V, VT, NH_, NH_);

    // xW + hid_bias -> bf16, stored in scan order
    gemm_bf16_kernel<<<4096, 256, 0, stream>>>(xbf, WT, hid_bias, xw,
                                               B_ * S_, G4_, NH_, 1);
    // sequential LSTM scan
    lstm_scan_kernel<<<SC_NWG, 512, 0, stream>>>(xw, UT, hseq, hbuf);
    // out = hseq @ V + out_bias -> f32
    gemm_bf16_kernel<<<1024, 256, 0, stream>>>(hseq, VT, out_bias, d_out,
                                               B_ * S_, NH_, NH_, 0);
}

// Round 8
// 5997.626 us; speedup vs baseline: 2.0680x; 1.0712x over previous
//
#include <hip/hip_runtime.h>

typedef unsigned short u16;
typedef unsigned int   u32;

typedef __attribute__((ext_vector_type(8)))  short bf16x8;
typedef __attribute__((ext_vector_type(4)))  float f32x4;
typedef __attribute__((ext_vector_type(4)))  u32   u32x4;
typedef __attribute__((ext_vector_type(16))) float f32x16;

#define B_  32
#define S_  1024
#define NH_ 512
#define G4_ 2048   // 4*NH
#define SC_NWG 8   // scan workgroups (8 waves each = 64 wave-slots)

__device__ __forceinline__ float bf2f(u16 h) {
    return __uint_as_float(((u32)h) << 16);
}
__device__ __forceinline__ u16 f2bf(float f) {
    u32 u = __float_as_uint(f);
    return (u16)((u + 0x7fffu + ((u >> 16) & 1u)) >> 16);
}
__device__ __forceinline__ float fsig(float x) {
    return 1.0f / (1.0f + __expf(-x));
}
__device__ __forceinline__ float ftanh(float x) {
    return 1.0f - 2.0f / (__expf(2.0f * x) + 1.0f);
}

// ---------------- fp32 -> bf16 elementwise convert (vectorized x4) ----------
__global__ void cvt_bf16_kernel(const float* __restrict__ in, u16* __restrict__ out, int n4) {
    int i = blockIdx.x * blockDim.x + threadIdx.x;
    if (i >= n4) return;
    f32x4 v = ((const f32x4*)in)[i];
    unsigned long long pk =
        (unsigned long long)f2bf(v[0]) |
        ((unsigned long long)f2bf(v[1]) << 16) |
        ((unsigned long long)f2bf(v[2]) << 32) |
        ((unsigned long long)f2bf(v[3]) << 48);
    ((unsigned long long*)out)[i] = pk;
}

// ---------------- fp32 [R][C] -> bf16 [C][R] transpose-convert --------------
__global__ void transpose_cvt_kernel(const float* __restrict__ in, u16* __restrict__ out,
                                     int R, int C) {
    __shared__ float tile[32][33];
    int bx = blockIdx.x, by = blockIdx.y;
    int tx = threadIdx.x & 31, ty = threadIdx.x >> 5;
    #pragma unroll
    for (int i = 0; i < 4; i++) {
        int r = by * 32 + ty + i * 8;
        tile[ty + i * 8][tx] = in[(size_t)r * C + bx * 32 + tx];
    }
    __syncthreads();
    #pragma unroll
    for (int i = 0; i < 4; i++) {
        int c = bx * 32 + ty + i * 8;
        out[(size_t)c * R + by * 32 + tx] = f2bf(tile[tx][ty + i * 8]);
    }
}

// ---------------- generic bf16 MFMA GEMM: C = A @ BT^T + bias ---------------
// A [M][K] bf16 row-major, BT [N][K] bf16, bias [N] f32.
// out_mode: 0 -> f32 row-major; 1 -> bf16 in SCAN ORDER [t][wg64][lane][r]
__global__ __launch_bounds__(256) void gemm_bf16_kernel(
    const u16* __restrict__ A, const u16* __restrict__ BT,
    const float* __restrict__ bias, void* __restrict__ Cp,
    int M, int N, int K, int out_mode)
{
    __shared__ u16 Al[128][40];
    __shared__ u16 Bl[128][40];
    int nbm = M >> 7;
    int bm = blockIdx.x % nbm, bn = blockIdx.x / nbm;
    int tid = threadIdx.x, lane = tid & 63, wave = tid >> 6;
    int wr = wave >> 1, wc = wave & 1;
    f32x4 acc[4][4];
    #pragma unroll
    for (int i = 0; i < 4; i++)
        #pragma unroll
        for (int j = 0; j < 4; j++)
            acc[i][j] = (f32x4){0.f, 0.f, 0.f, 0.f};
    int fr  = lane & 15;
    int kof = (lane >> 4) << 3;

    for (int k0 = 0; k0 < K; k0 += 32) {
        __syncthreads();
        #pragma unroll
        for (int i = 0; i < 2; i++) {
            int chunk = i * 256 + tid;
            int r = chunk >> 2, c = (chunk & 3) << 3;
            *(bf16x8*)&Al[r][c] = *(const bf16x8*)&A[(size_t)(bm * 128 + r) * K + k0 + c];
            *(bf16x8*)&Bl[r][c] = *(const bf16x8*)&BT[(size_t)(bn * 128 + r) * K + k0 + c];
        }
        __syncthreads();
        bf16x8 af[4], bfr[4];
        #pragma unroll
        for (int mi = 0; mi < 4; mi++)
            af[mi] = *(const bf16x8*)&Al[wr * 64 + mi * 16 + fr][kof];
        #pragma unroll
        for (int ni = 0; ni < 4; ni++)
            bfr[ni] = *(const bf16x8*)&Bl[wc * 64 + ni * 16 + fr][kof];
        #pragma unroll
        for (int mi = 0; mi < 4; mi++)
            #pragma unroll
            for (int ni = 0; ni < 4; ni++)
                acc[mi][ni] = __builtin_amdgcn_mfma_f32_16x16x32_bf16(af[mi], bfr[ni], acc[mi][ni], 0, 0, 0);
    }
    int rq = lane >> 4;
    #pragma unroll
    for (int mi = 0; mi < 4; mi++) {
        #pragma unroll
        for (int ni = 0; ni < 4; ni++) {
            int n = bn * 128 + wc * 64 + ni * 16 + fr;
            float bv = bias ? bias[n] : 0.f;
            #pragma unroll
            for (int r = 0; r < 4; r++) {
                int m = bm * 128 + wr * 64 + mi * 16 + rq * 4 + r;
                float v = acc[mi][ni][r] + bv;
                if (out_mode == 1) {
                    // scan-order store: [t][wg64][lane2][r2]  (validated round 4)
                    int t = m & 1023, b = m >> 10;
                    int g_loc = n >> 9, wg64i = (n >> 3) & 63, u_loc = n & 7;
                    int lane2 = (((b >> 2) & 1) << 5) | (u_loc << 2) | g_loc;
                    int r2 = (b & 3) | ((b >> 3) << 2);
                    ((u16*)Cp)[(((size_t)t * 64 + wg64i) * 64 + lane2) * 16 + r2] = f2bf(v);
                } else {
                    ((float*)Cp)[(size_t)m * N + n] = v;
                }
            }
        }
    }
}

// ---------------- LSTM scan: 8 persistent WGs x 8 waves ---------------------
// Hybrid protocol (system scope, verified r2/r4/r7):
//  * h words are tagged u32 (tag<<16 | bf16), tag = t+1, fire-and-forget.
//  * Each wave publishes flags[wg64]=t+1 right after issuing its h stores
//    (no drain). Flag RTT gives stores a head start.
//  * Consumer: concentrated poll of the 64 flag words (lane i reads flags[i],
//    one load/round) -> bulk-read slice once, validate all tags, retry on
//    miss (rare). One __syncthreads per step.
// Flow-control: a wave publishes t+1 only after finishing its step-t MFMA
// (which read h_lds of t), so poll-pass for t+1 implies all waves done
// reading the previous parity -> 2-deep hbuf ping-pong is overwrite-safe.
// Replay-safe: hbuf from a prior replay holds identical deterministic values
// (or 0xAA poison whose tag never matches); flags are re-zeroed per launch.
__global__ __launch_bounds__(512, 2) void lstm_scan_kernel(
    const u16* __restrict__ xw,    // [S][64][64][16] bf16 scan-order
    const u16* __restrict__ UT,    // [4H][NH] bf16
    u16* __restrict__ hseq,        // [B][S][NH] bf16
    u32* __restrict__ hbuf,        // [2][32][512] u32 tagged h
    u32* __restrict__ flags)       // [64] per-wave progress
{
    __shared__ u16 h_lds[32][520];      // [batch][k], +8 u16 pad (0-conflict, r2)
    __shared__ float gl[8][32][32];     // per-wave gate exchange

    const int tid  = threadIdx.x;
    const int wave = tid >> 6, lane = tid & 63;
    const int wg64 = (int)blockIdx.x * 8 + wave;
    const int col  = lane & 31, half = lane >> 5;
    const int u_loc = col >> 2, g_loc = col & 3;
    const int ucol  = g_loc * 512 + wg64 * 8 + u_loc;

    // persistent U B-fragments -- loaded once, then OPAQUED so the compiler
    // cannot rematerialize the loads inside the loop (r7: VGPR=112 proved it
    // was re-reading 32x16B from L2 every step). 128 VGPRs/lane.
    bf16x8 ufrag[32];
    #pragma unroll
    for (int kk = 0; kk < 32; kk++)
        ufrag[kk] = *(const bf16x8*)&UT[(size_t)ucol * 512 + kk * 16 + half * 8];
    #pragma unroll
    for (int kk = 0; kk < 32; kk++)
        asm volatile("" : "+v"(ufrag[kk]));

    float cst[4] = {0.f, 0.f, 0.f, 0.f};

    // h(0) = 0 in LDS (t=0 skips the poll)
    {
        bf16x8 z = (bf16x8){0, 0, 0, 0, 0, 0, 0, 0};
        bf16x8* hf = (bf16x8*)&h_lds[0][0];
        for (int i = tid; i < 2080; i += 512) hf[i] = z;
    }

    const int sb_b = tid >> 4;          // batch row this thread stages
    const int sb_i = tid & 15;          // 8-u32 (32B) chunk id within the row
    const u32* fp = flags + lane;       // lane i polls wave-slot i

    for (int t = 0; t < 1024; t++) {
        // xw for this step: 32B contiguous per lane, issued early
        const u16* xp = xw + ((size_t)((size_t)t * 64 + wg64) * 64 + lane) * 16;
        bf16x8 xv0 = *(const bf16x8*)xp;
        bf16x8 xv1 = *(const bf16x8*)(xp + 8);

        if (t > 0) {
            const u32 tg = (u32)t;
            // ---- concentrated flag poll: 64 words total, one load/round ----
            {
                u32 f;
                int rounds = 0;
                do {
                    asm volatile("global_load_dword %0, %1, off sc0 sc1\n\t"
                                 "s_waitcnt vmcnt(0)"
                                 : "=v"(f) : "v"(fp) : "memory");
                } while (!__all((int)(f >= tg)) && ++rounds < (1 << 17));
            }
            // ---- bulk-read slice, validate every tag, retry on miss --------
            const u32* src = hbuf + (((size_t)t & 1) << 14) + sb_b * 512 + sb_i * 8;
            u32x4 v0, v1, v2, v3, v4, v5, v6, v7;
            int retries = 0;
            while (1) {
                asm volatile(
                    "global_load_dwordx4 %0, %8, off sc0 sc1\n\t"
                    "global_load_dwordx4 %1, %8, off offset:16 sc0 sc1\n\t"
                    "global_load_dwordx4 %2, %8, off offset:512 sc0 sc1\n\t"
                    "global_load_dwordx4 %3, %8, off offset:528 sc0 sc1\n\t"
                    "global_load_dwordx4 %4, %8, off offset:1024 sc0 sc1\n\t"
                    "global_load_dwordx4 %5, %8, off offset:1040 sc0 sc1\n\t"
                    "global_load_dwordx4 %6, %8, off offset:1536 sc0 sc1\n\t"
                    "global_load_dwordx4 %7, %8, off offset:1552 sc0 sc1\n\t"
                    "s_waitcnt vmcnt(0)"
                    : "=&v"(v0), "=&v"(v1), "=&v"(v2), "=&v"(v3),
                      "=&v"(v4), "=&v"(v5), "=&v"(v6), "=&v"(v7)
                    : "v"(src) : "memory");
                u32 bad = 0;
                #pragma unroll
                for (int j = 0; j < 4; j++) {
                    bad |= (v0[j] >> 16) ^ tg; bad |= (v1[j] >> 16) ^ tg;
                    bad |= (v2[j] >> 16) ^ tg; bad |= (v3[j] >> 16) ^ tg;
                    bad |= (v4[j] >> 16) ^ tg; bad |= (v5[j] >> 16) ^ tg;
                    bad |= (v6[j] >> 16) ^ tg; bad |= (v7[j] >> 16) ^ tg;
                }
                if (!bad || ++retries > (1 << 14)) break;
            }
            __builtin_amdgcn_sched_barrier(0);
            // pack pairs -> bf16, write 4x16B at 256B stride (0-conflict, r2)
            u16* d = &h_lds[sb_b][sb_i * 8];
            u32x4 p;
            p[0] = (v0[0] & 0xffffu) | (v0[1] << 16);
            p[1] = (v0[2] & 0xffffu) | (v0[3] << 16);
            p[2] = (v1[0] & 0xffffu) | (v1[1] << 16);
            p[3] = (v1[2] & 0xffffu) | (v1[3] << 16);
            *(u32x4*)(d) = p;
            p[0] = (v2[0] & 0xffffu) | (v2[1] << 16);
            p[1] = (v2[2] & 0xffffu) | (v2[3] << 16);
            p[2] = (v3[0] & 0xffffu) | (v3[1] << 16);
            p[3] = (v3[2] & 0xffffu) | (v3[3] << 16);
            *(u32x4*)(d + 128) = p;
            p[0] = (v4[0] & 0xffffu) | (v4[1] << 16);
            p[1] = (v4[2] & 0xffffu) | (v4[3] << 16);
            p[2] = (v5[0] & 0xffffu) | (v5[1] << 16);
            p[3] = (v5[2] & 0xffffu) | (v5[3] << 16);
            *(u32x4*)(d + 256) = p;
            p[0] = (v6[0] & 0xffffu) | (v6[1] << 16);
            p[1] = (v6[2] & 0xffffu) | (v6[3] << 16);
            p[2] = (v7[0] & 0xffffu) | (v7[1] << 16);
            p[3] = (v7[2] & 0xffffu) | (v7[3] << 16);
            *(u32x4*)(d + 384) = p;
        }
        __syncthreads();

        // gates = h @ Uslice: 2 accumulators halve the dependent-MFMA chain
        f32x16 a0 = {0,0,0,0, 0,0,0,0, 0,0,0,0, 0,0,0,0};
        f32x16 a1 = {0,0,0,0, 0,0,0,0, 0,0,0,0, 0,0,0,0};
        #pragma unroll
        for (int kk = 0; kk < 16; kk++) {
            bf16x8 af0 = *(const bf16x8*)&h_lds[col][kk * 16 + half * 8];
            a0 = __builtin_amdgcn_mfma_f32_32x32x16_bf16(af0, ufrag[kk], a0, 0, 0, 0);
            bf16x8 af1 = *(const bf16x8*)&h_lds[col][(kk + 16) * 16 + half * 8];
            a1 = __builtin_amdgcn_mfma_f32_32x32x16_bf16(af1, ufrag[kk + 16], a1, 0, 0, 0);
        }

        // gate exchange (wave-local LDS; in-wave lgkmcnt ordering, no barrier)
        #pragma unroll
        for (int r = 0; r < 16; r++) {
            int b = (r & 3) + ((r >> 2) << 3) + (half << 2);
            float xwv = bf2f(r < 8 ? (u16)xv0[r] : (u16)xv1[r - 8]);
            gl[wave][b][col] = a0[r] + a1[r] + xwv;
        }

        // cell update: compute all 4 results first, then burst the stores
        u16 hv[4];
        int bi[4];
        #pragma unroll
        for (int i = 0; i < 4; i++) {
            int p = (i << 6) + lane, b = p >> 3, u = p & 7;
            f32x4 g4 = *(const f32x4*)&gl[wave][b][u << 2];   // i,f,g,o
            float si = fsig(g4[0]), sf = fsig(g4[1]);
            float sg = ftanh(g4[2]), so = fsig(g4[3]);
            float c = sf * cst[i] + si * sg;
            cst[i] = c;
            hv[i] = f2bf(so * ftanh(c));
            bi[i] = b;
        }
        // tagged h stores first (fire-and-forget), then the flag, then hseq
        u32* hb_out = hbuf + ((size_t)(((size_t)t + 1) & 1) << 14);
        const u32 tg1 = ((u32)(t + 1)) << 16;
        const int j = (wg64 << 3);
        #pragma unroll
        for (int i = 0; i < 4; i++) {
            int p = (i << 6) + lane, u = p & 7;
            u32 pk = tg1 | (u32)hv[i];
            u32* hp = hb_out + bi[i] * 512 + j + u;
            asm volatile("global_store_dword %0, %1, off sc0 sc1"
                         :: "v"(hp), "v"(pk) : "memory");
        }
        if (lane == 0) {
            u32 fv = (u32)(t + 1);
            u32* fq = flags + wg64;
            asm volatile("global_store_dword %0, %1, off sc0 sc1"
                         :: "v"(fq), "v"(fv) : "memory");
        }
        #pragma unroll
        for (int i = 0; i < 4; i++) {
            int p = (i << 6) + lane, u = p & 7;
            hseq[((size_t)bi[i] * S_ + t) * NH_ + j + u] = hv[i];
        }
    }
}

extern "C" void kernel_launch(void* const* d_in, const int* in_sizes, int n_in,
                              void* d_out, int out_size, void* d_ws, size_t ws_size,
                              hipStream_t stream) {
    const float* x        = (const float*)d_in[0];
    const float* W        = (const float*)d_in[1];
    const float* U        = (const float*)d_in[2];
    const float* hid_bias = (const float*)d_in[3];
    const float* V        = (const float*)d_in[4];
    const float* out_bias = (const float*)d_in[5];

    char* ws = (char*)d_ws;
    size_t off = 0;
    auto carve = [&](size_t bytes) -> void* {
        void* p = ws + off;
        off += (bytes + 255) & ~(size_t)255;
        return p;
    };
    u16* xw    = (u16*)carve((size_t)B_ * S_ * G4_ * 2);   // 128 MB, scan-order
    u16* xbf   = (u16*)carve((size_t)B_ * S_ * NH_ * 2);   //  32 MB
    u16* hseq  = (u16*)carve((size_t)B_ * S_ * NH_ * 2);   //  32 MB
    u16* WT    = (u16*)carve((size_t)G4_ * NH_ * 2);       //   2 MB
    u16* UT    = (u16*)carve((size_t)G4_ * NH_ * 2);       //   2 MB
    u16* VT    = (u16*)carve((size_t)NH_ * NH_ * 2);       // 512 KB
    u32* hbuf  = (u32*)carve((size_t)2 * B_ * NH_ * 4);    // 128 KB tagged h
    u32* flags = (u32*)carve(256);

    hipMemsetAsync(flags, 0, 256, stream);

    int n4 = B_ * S_ * NH_ / 4;
    cvt_bf16_kernel<<<(n4 + 255) / 256, 256, 0, stream>>>(x, xbf, n4);
    transpose_cvt_kernel<<<dim3(G4_ / 32, NH_ / 32), 256, 0, stream>>>(W, WT, NH_, G4_);
    transpose_cvt_kernel<<<dim3(G4_ / 32, NH_ / 32), 256, 0, stream>>>(U, UT, NH_, G4_);
    transpose_cvt_kernel<<<dim3(NH_ / 32, NH_ / 32), 256, 0, stream>>>(V, VT, NH_, NH_);

    // xW + hid_bias -> bf16, stored in scan order
    gemm_bf16_kernel<<<4096, 256, 0, stream>>>(xbf, WT, hid_bias, xw,
                                               B_ * S_, G4_, NH_, 1);
    // sequential LSTM scan
    lstm_scan_kernel<<<SC_NWG, 512, 0, stream>>>(xw, UT, hseq, hbuf, flags);
    // out = hseq @ V + out_bias -> f32
    gemm_bf16_kernel<<<1024, 256, 0, stream>>>(hseq, VT, out_bias, d_out,
                                               B_ * S_, NH_, NH_, 0);
}